// Round 1
// 151.587 us; speedup vs baseline: 1.0082x; 1.0082x over previous
//
#include <hip/hip_runtime.h>
#include <cstdint>
#include <cstddef>

// Problem constants
#define B_    16
#define S_    1024
#define D_    768
#define NS_   256
#define V_    128
#define C_    6
#define R_    512
#define REL_  97
#define HID_  384
#define DIS_  20
#define KD_   768    // K for both hoisted GEMMs (= D_)
#define N2P_  128    // gemm2 padded N

typedef unsigned short ushort_t;
typedef unsigned int   u32;
typedef short bf16x4 __attribute__((ext_vector_type(4)));
typedef short bf16x8 __attribute__((ext_vector_type(8)));
typedef float f32x4  __attribute__((ext_vector_type(4)));
typedef float f32x16 __attribute__((ext_vector_type(16)));

__device__ __forceinline__ float bf2f(short s) {
    return __uint_as_float(((unsigned int)(unsigned short)s) << 16);
}
__device__ __forceinline__ short f2bf(float x) {   // RNE
    union { float f; unsigned int u; } c; c.f = x;
    unsigned int r = (c.u + 0x7fffu + ((c.u >> 16) & 1u)) >> 16;
    return (short)(unsigned short)r;
}

// async global->LDS, 16 B per lane; LDS dest = wave-uniform base + lane*16
typedef const __attribute__((address_space(1))) u32* gas_t;
typedef __attribute__((address_space(3))) u32*       las_t;
__device__ __forceinline__ void dma16(const void* g, void* l) {
    __builtin_amdgcn_global_load_lds((gas_t)g, (las_t)l, 16, 0, 0);
}

// ---------------------------------------------------------------------------
// Kernel A (prep), 192 threads:
//  blocks [0,4096):      span max-pool -> span_emb (bf16)
//  blocks [4096,4480):   W1 head|tail slices -> W1HT tiles (K=768, N=768)
//                        n<384: W1[k][n] (head rows 0..767)
//                        n>=384: W1[788+k][n-384] (tail rows 788..1555)
//  blocks [4480,4672):   W1 prod slice (rows 1576..2343) -> W1P (K=768,N=384)
//  blocks [4672,4704):   W2 (384x97) -> W2T (128x384, n-padded)
//  blocks [4704,4784):   dis projection tables (f32, exact):
//                        disH[i][n] = sum_j dis[i][j]*W1[768+j][n]
//                        disT[i][n] = sum_j dis[i][j]*W1[1556+j][n]
// Tile layout for W1HT/W1P (consumed by dma16 B-staging):
//   elem (k = it*64+kg*8+j, n = nt*64+nn) at [((it*NT+nt)*8+kg)*512 + nn*8 + j]
// ---------------------------------------------------------------------------
__global__ __launch_bounds__(192) void prep_kernel(
    const float* __restrict__ sr, const int* __restrict__ spans,
    const float* __restrict__ W1, const float* __restrict__ W2,
    const float* __restrict__ dis,
    ushort_t* __restrict__ span_emb, ushort_t* __restrict__ W1HT,
    ushort_t* __restrict__ W1P, ushort_t* __restrict__ W2T,
    float* __restrict__ disH, float* __restrict__ disT)
{
    int blk = blockIdx.x;
    int tid = threadIdx.x;
    if (blk < 4096) {
        int bn    = blk;
        int b     = bn >> 8;                 // NS = 256
        int start = spans[2 * bn];
        int end   = spans[2 * bn + 1];
        int w     = end - start;             // 0..7, block-uniform
        const float* base = sr + ((size_t)b * S_ + start) * D_ + tid * 4;
        f32x4 x[8];
        x[0] = *(const f32x4*)base;
        switch (w) {                         // block-uniform fallthrough
        case 7: x[7] = *(const f32x4*)(base + 7 * D_); [[fallthrough]];
        case 6: x[6] = *(const f32x4*)(base + 6 * D_); [[fallthrough]];
        case 5: x[5] = *(const f32x4*)(base + 5 * D_); [[fallthrough]];
        case 4: x[4] = *(const f32x4*)(base + 4 * D_); [[fallthrough]];
        case 3: x[3] = *(const f32x4*)(base + 3 * D_); [[fallthrough]];
        case 2: x[2] = *(const f32x4*)(base + 2 * D_); [[fallthrough]];
        case 1: x[1] = *(const f32x4*)(base + 1 * D_); break;
        default: break;
        }
        f32x4 m = x[0];
#pragma unroll
        for (int j = 1; j < 8; ++j)
            if (j <= w) {
#pragma unroll
                for (int c = 0; c < 4; ++c) m[c] = fmaxf(m[c], x[j][c]);
            }
        bf16x4 o;
#pragma unroll
        for (int c = 0; c < 4; ++c) o[c] = f2bf(m[c]);
        *(bf16x4*)(span_emb + (size_t)bn * D_ + tid * 4) = o;
    } else if (blk < 4480) {                 // W1HT: 384 blocks, 73728 granules
        int flat = (blk - 4096) * 192 + tid;
        int nn   = flat & 63;
        int kg   = (flat >> 6) & 7;
        int itnt = flat >> 9;                // it*12 + nt, 0..143
        int it   = itnt / 12;
        int nt   = itnt - it * 12;
        bf16x8 p;
#pragma unroll
        for (int j = 0; j < 8; ++j) {
            int k = it * 64 + kg * 8 + j;
            int n = nt * 64 + nn;
            float v = (n < HID_) ? W1[(size_t)k * HID_ + n]
                                 : W1[(size_t)(788 + k) * HID_ + (n - HID_)];
            p[j] = f2bf(v);
        }
        *(bf16x8*)(W1HT + ((size_t)itnt * 8 + kg) * 512 + nn * 8) = p;
    } else if (blk < 4672) {                 // W1P: 192 blocks, 36864 granules
        int flat = (blk - 4480) * 192 + tid;
        int nn   = flat & 63;
        int kg   = (flat >> 6) & 7;
        int itnt = flat >> 9;                // it*6 + nt, 0..71
        int it   = itnt / 6;
        int nt   = itnt - it * 6;
        bf16x8 p;
#pragma unroll
        for (int j = 0; j < 8; ++j) {
            int k = it * 64 + kg * 8 + j;
            int n = nt * 64 + nn;
            p[j] = f2bf(W1[(size_t)(1576 + k) * HID_ + n]);
        }
        *(bf16x8*)(W1P + ((size_t)itnt * 8 + kg) * 512 + nn * 8) = p;
    } else if (blk < 4704) {                 // W2T: 32 blocks
        int g  = (blk - 4672) * 192 + tid;   // 0..6143 = 128*384/8
        int n  = g / 48;                     // 0..127
        int k0 = (g - n * 48) * 8;
        bf16x8 p;
#pragma unroll
        for (int j = 0; j < 8; ++j) {
            float v = (n < REL_) ? W2[(size_t)(k0 + j) * REL_ + n] : 0.f;
            p[j] = f2bf(v);
        }
        *(bf16x8*)(W2T + (size_t)n * HID_ + k0) = p;
    } else {                                 // dis tables: 80 blocks, 15360 outs
        int g   = (blk - 4704) * 192 + tid;  // 0..15359
        int sel = g >= 7680;
        int gg  = sel ? g - 7680 : g;
        int i   = gg / HID_;                 // 0..19
        int n   = gg - i * HID_;             // 0..383
        int rb  = sel ? 1556 : 768;
        float a = 0.f;
#pragma unroll
        for (int j = 0; j < DIS_; ++j)
            a += dis[i * DIS_ + j] * W1[(size_t)(rb + j) * HID_ + n];
        (sel ? disT : disH)[i * HID_ + n] = a;
    }
}

// ---------------------------------------------------------------------------
// Kernel 2: vertex mean (bf16 in/out, f32 accumulate).
// ---------------------------------------------------------------------------
__global__ __launch_bounds__(192) void vertex_kernel(
    const ushort_t* __restrict__ span_emb, const int* __restrict__ vidx,
    const int* __restrict__ vmask, ushort_t* __restrict__ vembB)
{
    int bv = blockIdx.x;
    int b  = bv >> 7;                // V = 128
    const int* vi = vidx  + bv * C_;
    const int* vm = vmask + bv * C_;
    int   idxs[C_];
    float ms[C_];
    float cnt = 0.f;
#pragma unroll
    for (int c = 0; c < C_; ++c) {
        idxs[c] = vi[c];
        ms[c]   = (float)vm[c];
        cnt    += ms[c];
    }
    float inv = 1.f / fmaxf(cnt, 1.f);
    int col = threadIdx.x * 4;
    float s[4] = {0.f, 0.f, 0.f, 0.f};
#pragma unroll
    for (int c = 0; c < C_; ++c) {
        if (ms[c] != 0.f) {          // block-uniform branch
            bf16x4 x = *(const bf16x4*)(span_emb +
                        ((size_t)(b * NS_ + idxs[c])) * D_ + col);
#pragma unroll
            for (int q = 0; q < 4; ++q) s[q] += bf2f(x[q]);
        }
    }
    bf16x4 o;
#pragma unroll
    for (int q = 0; q < 4; ++q) o[q] = f2bf(s[q] * inv);
    *(bf16x4*)(vembB + (size_t)bv * D_ + col) = o;
}

// ---------------------------------------------------------------------------
// Kernel 3 (GEMM C): vproj = vembB(2048x768) @ W1HT(768x768), f32 out.
// cols 0..383 = head projection, 384..767 = tail projection.
// Block 64m x 64n, 4 waves (2x2) each one 32x32 tile; LDS swizzled A + plane B.
// A LDS: Abuf[row][64], granule g of row r at slot (g+r)&7 (dma16 lane-linear).
// ---------------------------------------------------------------------------
__global__ __launch_bounds__(256, 3) void gemmc_kernel(
    const ushort_t* __restrict__ vembB, const ushort_t* __restrict__ W1HT,
    float* __restrict__ vproj)
{
    __shared__ ushort_t Abuf[2][64][64];
    __shared__ ushort_t Bbuf[2][8][64][8];

    int tid  = threadIdx.x;
    int wv   = tid >> 6;
    int lane = tid & 63;
    int m0   = blockIdx.x * 64;
    int nt   = blockIdx.y;
    int n0   = nt * 64;

    int rr  = lane >> 3;
    int sl  = lane & 7;
    int gsw = (sl - rr) & 7;

    const ushort_t* asrc[2];
#pragma unroll
    for (int gi = 0; gi < 2; ++gi)
        asrc[gi] = vembB + (size_t)(m0 + wv * 16 + gi * 8 + rr) * KD_ + gsw * 8;

    auto stage = [&](int bf, int it) {
#pragma unroll
        for (int gi = 0; gi < 2; ++gi)
            dma16(asrc[gi] + it * 64, &Abuf[bf][wv * 16 + gi * 8][0]);
        const ushort_t* bbase = W1HT + ((size_t)it * 12 + nt) * 4096;
#pragma unroll
        for (int q = 0; q < 2; ++q) {
            int p = wv * 2 + q;
            dma16(bbase + (size_t)p * 512 + lane * 8, &Bbuf[bf][p][0][0]);
        }
    };

    int half = lane >> 5;
    int lrow = lane & 31;
    int wm   = (wv & 1) * 32;
    int wn   = (wv >> 1) * 32;

    f32x16 acc;
#pragma unroll
    for (int r = 0; r < 16; ++r) acc[r] = 0.f;

    stage(0, 0);
    for (int it = 0; it < 12; ++it) {
        int bf = it & 1;
        __syncthreads();
        if (it + 1 < 12) stage(bf ^ 1, it + 1);
#pragma unroll
        for (int s = 0; s < 4; ++s) {
            int kg   = s * 2 + half;
            int slot = ((kg + lrow) & 7) * 8;
            bf16x8 a = *(bf16x8*)&Abuf[bf][wm + lrow][slot];
            bf16x8 b = *(bf16x8*)&Bbuf[bf][kg][wn + lrow][0];
            acc = __builtin_amdgcn_mfma_f32_32x32x16_bf16(a, b, acc, 0, 0, 0);
        }
    }

    // C/D 32x32 layout: col=lane&31, row=(reg&3)+8*(reg>>2)+4*(lane>>5)
    int col = n0 + wn + lrow;
#pragma unroll
    for (int r = 0; r < 16; ++r) {
        int row = m0 + wm + (r & 3) + 8 * (r >> 2) + 4 * half;
        vproj[(size_t)row * KD_ + col] = acc[r];
    }
}

// ---------------------------------------------------------------------------
// Kernel 4 (GEMM D): pair-product GEMM + additive epilogue.
// A[r][k] = head[r][k]*tail[r][k] (bf16, computed in staging from vembB),
// B = W1P (768x384). hidden[r][n] = relu(acc + vprojH[h] + vprojT[t]
//                                        + disH[dht] + disT[dth]) -> bf16.
// Grid 128 x 6 = 768 blocks -> exactly 3 blocks/CU. LDS ~33 KB.
// ---------------------------------------------------------------------------
__global__ __launch_bounds__(256, 3) void gemmd_kernel(
    const ushort_t* __restrict__ vembB, const int* __restrict__ ht,
    const int* __restrict__ dht, const int* __restrict__ dth,
    const ushort_t* __restrict__ W1P, const float* __restrict__ vproj,
    const float* __restrict__ disH, const float* __restrict__ disT,
    ushort_t* __restrict__ hidden)
{
    __shared__ ushort_t Abuf[2][64][64];
    __shared__ ushort_t Bbuf[2][8][64][8];
    __shared__ int hI[64], tI[64], dhI[64], dtI[64];

    int tid  = threadIdx.x;
    int wv   = tid >> 6;
    int lane = tid & 63;
    int m0   = blockIdx.x * 64;
    int nt   = blockIdx.y;
    int n0   = nt * 64;

    int rr  = lane >> 3;
    int sl  = lane & 7;
    int gsw = (sl - rr) & 7;

    if (tid < 64) {                          // epilogue index stash
        int g = m0 + tid;
        int b = g >> 9;                      // R = 512
        hI[tid]  = b * V_ + ht[2 * g];
        tI[tid]  = b * V_ + ht[2 * g + 1];
        dhI[tid] = dht[g];
        dtI[tid] = dth[g];
    }

    int hoff[2], toff[2];
#pragma unroll
    for (int gi = 0; gi < 2; ++gi) {
        int g = m0 + wv * 16 + gi * 8 + rr;
        int b = g >> 9;
        hoff[gi] = (b * V_ + ht[2 * g])     * KD_;
        toff[gi] = (b * V_ + ht[2 * g + 1]) * KD_;
    }

    auto stage = [&](int bf, int it) {
        int kk = it * 64 + gsw * 8;
#pragma unroll
        for (int gi = 0; gi < 2; ++gi) {
            bf16x8 h = *(const bf16x8*)(vembB + hoff[gi] + kk);
            bf16x8 t = *(const bf16x8*)(vembB + toff[gi] + kk);
            bf16x8 p;
#pragma unroll
            for (int j = 0; j < 8; ++j) p[j] = f2bf(bf2f(h[j]) * bf2f(t[j]));
            *(bf16x8*)&Abuf[bf][wv * 16 + gi * 8 + rr][sl * 8] = p;
        }
        const ushort_t* bbase = W1P + ((size_t)it * 6 + nt) * 4096;
#pragma unroll
        for (int q = 0; q < 2; ++q) {
            int p = wv * 2 + q;
            dma16(bbase + (size_t)p * 512 + lane * 8, &Bbuf[bf][p][0][0]);
        }
    };

    int half = lane >> 5;
    int lrow = lane & 31;
    int wm   = (wv & 1) * 32;
    int wn   = (wv >> 1) * 32;

    f32x16 acc;
#pragma unroll
    for (int r = 0; r < 16; ++r) acc[r] = 0.f;

    stage(0, 0);
    for (int it = 0; it < 12; ++it) {
        int bf = it & 1;
        __syncthreads();                     // drains DMA + ds_writes + reads
        if (it + 1 < 12) stage(bf ^ 1, it + 1);
#pragma unroll
        for (int s = 0; s < 4; ++s) {
            int kg   = s * 2 + half;
            int slot = ((kg + lrow) & 7) * 8;
            bf16x8 a = *(bf16x8*)&Abuf[bf][wm + lrow][slot];
            bf16x8 b = *(bf16x8*)&Bbuf[bf][kg][wn + lrow][0];
            acc = __builtin_amdgcn_mfma_f32_32x32x16_bf16(a, b, acc, 0, 0, 0);
        }
    }

    int col = n0 + wn + lrow;
#pragma unroll
    for (int r = 0; r < 16; ++r) {
        int rl = wm + (r & 3) + 8 * (r >> 2) + 4 * half;   // local row 0..63
        float v = acc[r]
                + vproj[(size_t)hI[rl] * KD_ + col]
                + vproj[(size_t)tI[rl] * KD_ + HID_ + col]
                + disH[dhI[rl] * HID_ + col]
                + disT[dtI[rl] * HID_ + col];
        hidden[(size_t)(m0 + rl) * HID_ + col] = (ushort_t)f2bf(fmaxf(v, 0.f));
    }
}

// ---------------------------------------------------------------------------
// Kernel 5: MFMA GEMM2 + bias; A = hidden (already relu'd bf16, one slice).
// ---------------------------------------------------------------------------
__global__ __launch_bounds__(256) void gemm2_kernel(
    const ushort_t* __restrict__ hidden, const ushort_t* __restrict__ W2T,
    const float* __restrict__ b2, float* __restrict__ out)
{
    __shared__ ushort_t As[32][72];
    __shared__ ushort_t Bs[128][72];

    int m0  = blockIdx.x * 32;
    int tid = threadIdx.x;

    int arow = tid >> 3;             // 0..31
    int akk  = (tid & 7) * 8;

    bf16x8 pA; bf16x8 pB[4];
    auto loadAB = [&](int k0) {
        pA = *(const bf16x8*)(hidden + (size_t)(m0 + arow) * HID_ + k0 + akk);
#pragma unroll
        for (int e = 0; e < 4; ++e)
            pB[e] = *(const bf16x8*)(W2T + (size_t)(arow + e * 32) * HID_ + k0 + akk);
    };

    int w    = tid >> 6;
    int lane = tid & 63;
    int wm = (w & 1) * 16;
    int wn = (w >> 1) * 64;
    int lr = lane & 15, lq = lane >> 4;

    f32x4 acc[4];
#pragma unroll
    for (int e = 0; e < 4; ++e) acc[e] = (f32x4){0.f, 0.f, 0.f, 0.f};

    loadAB(0);
    for (int k0 = 0; k0 < HID_; k0 += 64) {
        __syncthreads();
        *(bf16x8*)&As[arow][akk] = pA;
#pragma unroll
        for (int e = 0; e < 4; ++e)
            *(bf16x8*)&Bs[arow + e * 32][akk] = pB[e];
        __syncthreads();
        if (k0 + 64 < HID_) loadAB(k0 + 64);
#pragma unroll
        for (int ks = 0; ks < 2; ++ks) {
            int kb = ks * 32 + lq * 8;
            bf16x8 a = *(bf16x8*)&As[wm + lr][kb];
#pragma unroll
            for (int nf = 0; nf < 4; ++nf) {
                bf16x8 bb = *(bf16x8*)&Bs[wn + nf * 16 + lr][kb];
                acc[nf] = __builtin_amdgcn_mfma_f32_16x16x32_bf16(a, bb, acc[nf], 0, 0, 0);
            }
        }
    }

    int grow = m0 + wm + lq * 4;
#pragma unroll
    for (int nf = 0; nf < 4; ++nf) {
        int col = wn + nf * 16 + lr;
        if (col < REL_) {
            float bias = b2[col];
#pragma unroll
            for (int r = 0; r < 4; ++r)
                out[(size_t)(grow + r) * REL_ + col] = acc[nf][r] + bias;
        }
    }
}

// ---------------------------------------------------------------------------
extern "C" void kernel_launch(void* const* d_in, const int* in_sizes, int n_in,
                              void* d_out, int out_size, void* d_ws, size_t ws_size,
                              hipStream_t stream)
{
    const float* sr    = (const float*)d_in[0];
    const int*   spans = (const int*)  d_in[1];
    const int*   vidx  = (const int*)  d_in[3];
    const int*   vmask = (const int*)  d_in[4];
    const int*   ht    = (const int*)  d_in[5];
    const int*   dht   = (const int*)  d_in[7];
    const int*   dth   = (const int*)  d_in[8];
    const float* dis   = (const float*)d_in[9];
    const float* W1    = (const float*)d_in[10];
    const float* W2    = (const float*)d_in[11];
    const float* b2    = (const float*)d_in[12];
    float* out = (float*)d_out;

    // ws layout (bf16 regions first, then f32), ~24 MB total:
    ushort_t* span_emb = (ushort_t*)d_ws;                     // 4096*768
    ushort_t* vembB    = span_emb + (size_t)B_ * NS_ * D_;    // 2048*768
    ushort_t* W1HT     = vembB + (size_t)B_ * V_ * D_;        // 144*4096
    ushort_t* W1P      = W1HT + (size_t)144 * 4096;           // 72*4096
    ushort_t* W2T      = W1P + (size_t)72 * 4096;             // 128*384
    ushort_t* hidden   = W2T + (size_t)N2P_ * HID_;           // 8192*384
    float* vproj = (float*)(hidden + (size_t)B_ * R_ * HID_); // 2048*768 f32
    float* disH  = vproj + (size_t)B_ * V_ * KD_;             // 20*384 f32
    float* disT  = disH + (size_t)DIS_ * HID_;                // 20*384 f32

    prep_kernel<<<4784, 192, 0, stream>>>(
        sr, spans, W1, W2, dis, span_emb, W1HT, W1P, W2T, disH, disT);
    vertex_kernel<<<B_ * V_, 192, 0, stream>>>(span_emb, vidx, vmask, vembB);

    gemmc_kernel<<<dim3(32, 12), 256, 0, stream>>>(vembB, W1HT, vproj);
    gemmd_kernel<<<dim3(128, 6), 256, 0, stream>>>(
        vembB, ht, dht, dth, W1P, vproj, disH, disT, hidden);

    gemm2_kernel<<<(B_ * R_) / 32, 256, 0, stream>>>(hidden, W2T, b2, out);
}

// Round 3
// 149.908 us; speedup vs baseline: 1.0195x; 1.0112x over previous
//
#include <hip/hip_runtime.h>
#include <hip/hip_cooperative_groups.h>
#include <cstdint>
#include <cstddef>

namespace cg = cooperative_groups;

// Problem constants
#define B_    16
#define S_    1024
#define D_    768
#define NS_   256
#define V_    128
#define C_    6
#define R_    512
#define REL_  97
#define HID_  384
#define DIS_  20
#define KD_   768    // K for both hoisted GEMMs (= D_)
#define N2P_  128    // gemm2 padded N
#define NBLK  768    // cooperative grid target: 3 blocks/CU x 256 CUs
#define NTHR  256

typedef unsigned short ushort_t;
typedef unsigned int   u32;
typedef short bf16x4 __attribute__((ext_vector_type(4)));
typedef short bf16x8 __attribute__((ext_vector_type(8)));
typedef float f32x4  __attribute__((ext_vector_type(4)));
typedef float f32x16 __attribute__((ext_vector_type(16)));

__device__ __forceinline__ float bf2f(short s) {
    return __uint_as_float(((unsigned int)(unsigned short)s) << 16);
}
__device__ __forceinline__ short f2bf(float x) {   // RNE
    union { float f; unsigned int u; } c; c.f = x;
    unsigned int r = (c.u + 0x7fffu + ((c.u >> 16) & 1u)) >> 16;
    return (short)(unsigned short)r;
}

// async global->LDS, 16 B per lane; LDS dest = wave-uniform base + lane*16
typedef const __attribute__((address_space(1))) u32* gas_t;
typedef __attribute__((address_space(3))) u32*       las_t;
__device__ __forceinline__ void dma16(const void* g, void* l) {
    __builtin_amdgcn_global_load_lds((gas_t)g, (las_t)l, 16, 0, 0);
}

// ===========================================================================
// PATH A: single cooperative mega-kernel (grid-size-agnostic task loops).
// Phases separated by grid.sync():
//  P0a span max-pool   (12288 wave-tasks: 4096 spans x 3 col-thirds)
//  P0b weight repacks + exact-f32 dis projection tables (132096 thread-tasks)
//  P1  vertex mean     (393216 thread-tasks of 4 cols)
//  P2  GEMM C: vproj = vembB(2048x768) @ W1HT(768x768)   [384 block-tasks]
//  P3  GEMM D: (h.t)@W1P + gathered adds + relu -> hidden [768 block-tasks]
//  P4  GEMM 2: out = hidden @ W2T + b2                    [256 block-tasks]
// ===========================================================================
__global__ __launch_bounds__(NTHR, 3) void mega_kernel(
    const float* __restrict__ sr, const int* __restrict__ spans,
    const int* __restrict__ vidx, const int* __restrict__ vmask,
    const int* __restrict__ ht, const int* __restrict__ dht,
    const int* __restrict__ dth, const float* __restrict__ dis,
    const float* __restrict__ W1, const float* __restrict__ W2,
    const float* __restrict__ b2,
    ushort_t* __restrict__ span_emb, ushort_t* __restrict__ vembB,
    ushort_t* __restrict__ W1HT, ushort_t* __restrict__ W1P,
    ushort_t* __restrict__ W2T, float* __restrict__ disH,
    float* __restrict__ disT, ushort_t* __restrict__ hidden,
    float* __restrict__ vproj, float* __restrict__ out)
{
    cg::grid_group grid = cg::this_grid();

    __shared__ union {
        struct {
            ushort_t A[2][64][64];        // 16 KB (swizzled slots)
            ushort_t Bp[2][8][64][8];     // 16 KB (granule planes)
            int hI[64], tI[64], dhI[64], dtI[64];
        } cd;
        struct {
            ushort_t As[32][72];
            ushort_t Bs[128][72];
        } g2;
    } sm;

    const int tid   = threadIdx.x;
    const int blk   = blockIdx.x;
    const int lane  = tid & 63;
    const int wv    = tid >> 6;
    const int nblks = gridDim.x;
    const int gtid  = blk * NTHR + tid;
    const int nthrd = nblks * NTHR;

    // ---------------- P0a: span max-pool (wave-task loop) ----------------
    {
        const int waveid = blk * 4 + wv;
        const int nwaves = nblks * 4;
        for (int task = waveid; task < 12288; task += nwaves) {
            int bn = task & 4095;
            int q  = task >> 12;                // col third
            int b  = bn >> 8;                   // NS = 256
            int start = spans[2 * bn];
            int end   = spans[2 * bn + 1];
            int w     = end - start;            // 0..7, wave-uniform
            int col   = q * 256 + lane * 4;
            const float* base = sr + ((size_t)b * S_ + start) * D_ + col;
            f32x4 x[8];
            x[0] = *(const f32x4*)base;
            switch (w) {                        // wave-uniform fallthrough
            case 7: x[7] = *(const f32x4*)(base + 7 * D_); [[fallthrough]];
            case 6: x[6] = *(const f32x4*)(base + 6 * D_); [[fallthrough]];
            case 5: x[5] = *(const f32x4*)(base + 5 * D_); [[fallthrough]];
            case 4: x[4] = *(const f32x4*)(base + 4 * D_); [[fallthrough]];
            case 3: x[3] = *(const f32x4*)(base + 3 * D_); [[fallthrough]];
            case 2: x[2] = *(const f32x4*)(base + 2 * D_); [[fallthrough]];
            case 1: x[1] = *(const f32x4*)(base + 1 * D_); break;
            default: break;
            }
            f32x4 m = x[0];
#pragma unroll
            for (int j = 1; j < 8; ++j)
                if (j <= w) {
#pragma unroll
                    for (int c = 0; c < 4; ++c) m[c] = fmaxf(m[c], x[j][c]);
                }
            bf16x4 o;
#pragma unroll
            for (int c = 0; c < 4; ++c) o[c] = f2bf(m[c]);
            *(bf16x4*)(span_emb + (size_t)bn * D_ + col) = o;
        }
    }
    // ---------------- P0b: weight repacks + dis tables ----------------
    for (int g0 = gtid; g0 < 132096; g0 += nthrd) {
        if (g0 < 73728) {                       // W1HT granules (144*8*64)
            int g = g0;
            int nn = g & 63, kg = (g >> 6) & 7, itnt = g >> 9;  // 0..143
            int it = itnt / 12, nt = itnt - it * 12;
            bf16x8 p;
#pragma unroll
            for (int j = 0; j < 8; ++j) {
                int k = it * 64 + kg * 8 + j;
                int n = nt * 64 + nn;
                float v = (n < HID_) ? W1[(size_t)k * HID_ + n]
                                     : W1[(size_t)(788 + k) * HID_ + (n - HID_)];
                p[j] = f2bf(v);
            }
            *(bf16x8*)(W1HT + ((size_t)itnt * 8 + kg) * 512 + nn * 8) = p;
        } else if (g0 < 110592) {               // W1P granules (72*8*64)
            int g = g0 - 73728;
            int nn = g & 63, kg = (g >> 6) & 7, itnt = g >> 9;  // 0..71
            int it = itnt / 6, nt = itnt - it * 6;
            bf16x8 p;
#pragma unroll
            for (int j = 0; j < 8; ++j) {
                int k = it * 64 + kg * 8 + j;
                int n = nt * 64 + nn;
                p[j] = f2bf(W1[(size_t)(1576 + k) * HID_ + n]);
            }
            *(bf16x8*)(W1P + ((size_t)itnt * 8 + kg) * 512 + nn * 8) = p;
        } else if (g0 < 116736) {               // W2T granules (128*48)
            int g = g0 - 110592;
            int n = g / 48, k0 = (g - n * 48) * 8;
            bf16x8 p;
#pragma unroll
            for (int j = 0; j < 8; ++j) {
                float v = (n < REL_) ? W2[(size_t)(k0 + j) * REL_ + n] : 0.f;
                p[j] = f2bf(v);
            }
            *(bf16x8*)(W2T + (size_t)n * HID_ + k0) = p;
        } else {                                // dis tables (2*20*384)
            int g = g0 - 116736;
            int sel = g >= 7680;
            int gg = sel ? g - 7680 : g;
            int i = gg / HID_, n = gg - (gg / HID_) * HID_;
            int rb = sel ? 1556 : 768;
            float a = 0.f;
#pragma unroll
            for (int j = 0; j < DIS_; ++j)
                a += dis[i * DIS_ + j] * W1[(size_t)(rb + j) * HID_ + n];
            (sel ? disT : disH)[i * HID_ + n] = a;
        }
    }

    grid.sync();

    // ---------------- P1: vertex mean (thread-task loop, 4 cols each) ------
    for (int task = gtid; task < 393216; task += nthrd) {
        int bv  = task / 192;
        int grp = task - bv * 192;
        int b   = bv >> 7;                      // V = 128
        const int* vi = vidx  + bv * C_;
        const int* vm = vmask + bv * C_;
        float cnt = 0.f;
        float sacc[4] = {0.f, 0.f, 0.f, 0.f};
        int col = grp * 4;
#pragma unroll
        for (int c = 0; c < C_; ++c) {
            int mc = vm[c];
            cnt += (float)mc;
            if (mc) {
                bf16x4 x = *(const bf16x4*)(span_emb +
                            ((size_t)(b * NS_ + vi[c])) * D_ + col);
#pragma unroll
                for (int q = 0; q < 4; ++q) sacc[q] += bf2f(x[q]);
            }
        }
        float inv = 1.f / fmaxf(cnt, 1.f);
        bf16x4 o;
#pragma unroll
        for (int q = 0; q < 4; ++q) o[q] = f2bf(sacc[q] * inv);
        *(bf16x4*)(vembB + (size_t)bv * D_ + col) = o;
    }

    grid.sync();

    // ---------------- P2: GEMM C (384 block-tasks) ----------------
    for (int bt = blk; bt < 384; bt += nblks) {
        const int mb = bt & 31, nt = bt >> 5;
        const int m0 = mb * 64, n0 = nt * 64;
        const int rr = lane >> 3, sl = lane & 7;
        const int gsw = (sl - rr) & 7;

        const ushort_t* asrc0 = vembB + (size_t)(m0 + wv * 16 + rr) * KD_ + gsw * 8;
        const ushort_t* asrc1 = asrc0 + 8 * KD_;

        auto stageC = [&](int bf, int it) {
            dma16(asrc0 + it * 64, &sm.cd.A[bf][wv * 16][0]);
            dma16(asrc1 + it * 64, &sm.cd.A[bf][wv * 16 + 8][0]);
            const ushort_t* bbase = W1HT + ((size_t)it * 12 + nt) * 4096;
#pragma unroll
            for (int q = 0; q < 2; ++q) {
                int p = wv * 2 + q;
                dma16(bbase + (size_t)p * 512 + lane * 8, &sm.cd.Bp[bf][p][0][0]);
            }
        };

        const int half = lane >> 5, lrow = lane & 31;
        const int wm = (wv & 1) * 32, wn = (wv >> 1) * 32;

        f32x16 acc;
#pragma unroll
        for (int r = 0; r < 16; ++r) acc[r] = 0.f;

        stageC(0, 0);
        for (int it = 0; it < 12; ++it) {
            int bf = it & 1;
            __syncthreads();
            if (it + 1 < 12) stageC(bf ^ 1, it + 1);
#pragma unroll
            for (int s = 0; s < 4; ++s) {
                int kg   = s * 2 + half;
                int slot = ((kg + lrow) & 7) * 8;
                bf16x8 a = *(bf16x8*)&sm.cd.A[bf][wm + lrow][slot];
                bf16x8 b = *(bf16x8*)&sm.cd.Bp[bf][kg][wn + lrow][0];
                acc = __builtin_amdgcn_mfma_f32_32x32x16_bf16(a, b, acc, 0, 0, 0);
            }
        }
        int col = n0 + wn + lrow;
#pragma unroll
        for (int r = 0; r < 16; ++r) {
            int row = m0 + wm + (r & 3) + 8 * (r >> 2) + 4 * half;
            vproj[(size_t)row * KD_ + col] = acc[r];
        }
    }

    grid.sync();

    // ---------------- P3: GEMM D (768 block-tasks) ----------------
    for (int bt = blk; bt < 768; bt += nblks) {
        __syncthreads();                         // protect hI stash reuse
        const int mb = bt & 127, nt = bt >> 7;
        const int m0 = mb * 64, n0 = nt * 64;
        const int rr = lane >> 3, sl = lane & 7;
        const int gsw = (sl - rr) & 7;

        if (tid < 64) {                          // epilogue index stash
            int g = m0 + tid;
            int b = g >> 9;                      // R = 512
            sm.cd.hI[tid]  = b * V_ + ht[2 * g];
            sm.cd.tI[tid]  = b * V_ + ht[2 * g + 1];
            sm.cd.dhI[tid] = dht[g];
            sm.cd.dtI[tid] = dth[g];
        }

        int hoff[2], toff[2];
#pragma unroll
        for (int gi = 0; gi < 2; ++gi) {
            int g = m0 + wv * 16 + gi * 8 + rr;
            int b = g >> 9;
            hoff[gi] = (b * V_ + ht[2 * g])     * KD_;
            toff[gi] = (b * V_ + ht[2 * g + 1]) * KD_;
        }

        auto stageD = [&](int bf, int it) {
            int kk = it * 64 + gsw * 8;
#pragma unroll
            for (int gi = 0; gi < 2; ++gi) {
                bf16x8 h = *(const bf16x8*)(vembB + hoff[gi] + kk);
                bf16x8 t = *(const bf16x8*)(vembB + toff[gi] + kk);
                bf16x8 p;
#pragma unroll
                for (int j = 0; j < 8; ++j) p[j] = f2bf(bf2f(h[j]) * bf2f(t[j]));
                *(bf16x8*)&sm.cd.A[bf][wv * 16 + gi * 8 + rr][sl * 8] = p;
            }
            const ushort_t* bbase = W1P + ((size_t)it * 6 + nt) * 4096;
#pragma unroll
            for (int q = 0; q < 2; ++q) {
                int p = wv * 2 + q;
                dma16(bbase + (size_t)p * 512 + lane * 8, &sm.cd.Bp[bf][p][0][0]);
            }
        };

        const int half = lane >> 5, lrow = lane & 31;
        const int wm = (wv & 1) * 32, wn = (wv >> 1) * 32;

        f32x16 acc;
#pragma unroll
        for (int r = 0; r < 16; ++r) acc[r] = 0.f;

        stageD(0, 0);
        for (int it = 0; it < 12; ++it) {
            int bf = it & 1;
            __syncthreads();
            if (it + 1 < 12) stageD(bf ^ 1, it + 1);
#pragma unroll
            for (int s = 0; s < 4; ++s) {
                int kg   = s * 2 + half;
                int slot = ((kg + lrow) & 7) * 8;
                bf16x8 a = *(bf16x8*)&sm.cd.A[bf][wm + lrow][slot];
                bf16x8 b = *(bf16x8*)&sm.cd.Bp[bf][kg][wn + lrow][0];
                acc = __builtin_amdgcn_mfma_f32_32x32x16_bf16(a, b, acc, 0, 0, 0);
            }
        }

        int col = n0 + wn + lrow;
#pragma unroll
        for (int r = 0; r < 16; ++r) {
            int rl = wm + (r & 3) + 8 * (r >> 2) + 4 * half;
            float v = acc[r]
                    + vproj[(size_t)sm.cd.hI[rl] * KD_ + col]
                    + vproj[(size_t)sm.cd.tI[rl] * KD_ + HID_ + col]
                    + disH[sm.cd.dhI[rl] * HID_ + col]
                    + disT[sm.cd.dtI[rl] * HID_ + col];
            hidden[(size_t)(m0 + rl) * HID_ + col] = (ushort_t)f2bf(fmaxf(v, 0.f));
        }
    }

    grid.sync();

    // ---------------- P4: GEMM 2 (256 block-tasks) ----------------
    for (int bt = blk; bt < 256; bt += nblks) {
        const int m0 = bt * 32;
        const int arow = tid >> 3;              // 0..31
        const int akk  = (tid & 7) * 8;

        bf16x8 pA; bf16x8 pB[4];
        auto loadAB = [&](int k0) {
            pA = *(const bf16x8*)(hidden + (size_t)(m0 + arow) * HID_ + k0 + akk);
#pragma unroll
            for (int e = 0; e < 4; ++e)
                pB[e] = *(const bf16x8*)(W2T + (size_t)(arow + e * 32) * HID_ + k0 + akk);
        };

        const int wm = (wv & 1) * 16, wn = (wv >> 1) * 64;
        const int lr = lane & 15, lq = lane >> 4;

        f32x4 acc[4];
#pragma unroll
        for (int e = 0; e < 4; ++e) acc[e] = (f32x4){0.f, 0.f, 0.f, 0.f};

        loadAB(0);
        for (int k0 = 0; k0 < HID_; k0 += 64) {
            __syncthreads();
            *(bf16x8*)&sm.g2.As[arow][akk] = pA;
#pragma unroll
            for (int e = 0; e < 4; ++e)
                *(bf16x8*)&sm.g2.Bs[arow + e * 32][akk] = pB[e];
            __syncthreads();
            if (k0 + 64 < HID_) loadAB(k0 + 64);
#pragma unroll
            for (int ks = 0; ks < 2; ++ks) {
                int kb = ks * 32 + lq * 8;
                bf16x8 a = *(bf16x8*)&sm.g2.As[wm + lr][kb];
#pragma unroll
                for (int nf = 0; nf < 4; ++nf) {
                    bf16x8 bb = *(bf16x8*)&sm.g2.Bs[wn + nf * 16 + lr][kb];
                    acc[nf] = __builtin_amdgcn_mfma_f32_16x16x32_bf16(a, bb, acc[nf], 0, 0, 0);
                }
            }
        }

        int grow = m0 + wm + lq * 4;
#pragma unroll
        for (int nf = 0; nf < 4; ++nf) {
            int col = wn + nf * 16 + lr;
            if (col < REL_) {
                float bias = b2[col];
#pragma unroll
                for (int r = 0; r < 4; ++r)
                    out[(size_t)(grow + r) * REL_ + col] = acc[nf][r] + bias;
            }
        }
    }
}

// ===========================================================================
// PATH B (fallback): verbatim round-1 five-kernel pipeline (verified 151.6us).
// ===========================================================================
__global__ __launch_bounds__(192) void prep_kernel(
    const float* __restrict__ sr, const int* __restrict__ spans,
    const float* __restrict__ W1, const float* __restrict__ W2,
    const float* __restrict__ dis,
    ushort_t* __restrict__ span_emb, ushort_t* __restrict__ W1HT,
    ushort_t* __restrict__ W1P, ushort_t* __restrict__ W2T,
    float* __restrict__ disH, float* __restrict__ disT)
{
    int blk = blockIdx.x;
    int tid = threadIdx.x;
    if (blk < 4096) {
        int bn    = blk;
        int b     = bn >> 8;
        int start = spans[2 * bn];
        int end   = spans[2 * bn + 1];
        int w     = end - start;
        const float* base = sr + ((size_t)b * S_ + start) * D_ + tid * 4;
        f32x4 x[8];
        x[0] = *(const f32x4*)base;
        switch (w) {
        case 7: x[7] = *(const f32x4*)(base + 7 * D_); [[fallthrough]];
        case 6: x[6] = *(const f32x4*)(base + 6 * D_); [[fallthrough]];
        case 5: x[5] = *(const f32x4*)(base + 5 * D_); [[fallthrough]];
        case 4: x[4] = *(const f32x4*)(base + 4 * D_); [[fallthrough]];
        case 3: x[3] = *(const f32x4*)(base + 3 * D_); [[fallthrough]];
        case 2: x[2] = *(const f32x4*)(base + 2 * D_); [[fallthrough]];
        case 1: x[1] = *(const f32x4*)(base + 1 * D_); break;
        default: break;
        }
        f32x4 m = x[0];
#pragma unroll
        for (int j = 1; j < 8; ++j)
            if (j <= w) {
#pragma unroll
                for (int c = 0; c < 4; ++c) m[c] = fmaxf(m[c], x[j][c]);
            }
        bf16x4 o;
#pragma unroll
        for (int c = 0; c < 4; ++c) o[c] = f2bf(m[c]);
        *(bf16x4*)(span_emb + (size_t)bn * D_ + tid * 4) = o;
    } else if (blk < 4480) {
        int flat = (blk - 4096) * 192 + tid;
        int nn   = flat & 63;
        int kg   = (flat >> 6) & 7;
        int itnt = flat >> 9;
        int it   = itnt / 12;
        int nt   = itnt - it * 12;
        bf16x8 p;
#pragma unroll
        for (int j = 0; j < 8; ++j) {
            int k = it * 64 + kg * 8 + j;
            int n = nt * 64 + nn;
            float v = (n < HID_) ? W1[(size_t)k * HID_ + n]
                                 : W1[(size_t)(788 + k) * HID_ + (n - HID_)];
            p[j] = f2bf(v);
        }
        *(bf16x8*)(W1HT + ((size_t)itnt * 8 + kg) * 512 + nn * 8) = p;
    } else if (blk < 4672) {
        int flat = (blk - 4480) * 192 + tid;
        int nn   = flat & 63;
        int kg   = (flat >> 6) & 7;
        int itnt = flat >> 9;
        int it   = itnt / 6;
        int nt   = itnt - it * 6;
        bf16x8 p;
#pragma unroll
        for (int j = 0; j < 8; ++j) {
            int k = it * 64 + kg * 8 + j;
            int n = nt * 64 + nn;
            p[j] = f2bf(W1[(size_t)(1576 + k) * HID_ + n]);
        }
        *(bf16x8*)(W1P + ((size_t)itnt * 8 + kg) * 512 + nn * 8) = p;
    } else if (blk < 4704) {
        int g  = (blk - 4672) * 192 + tid;
        int n  = g / 48;
        int k0 = (g - n * 48) * 8;
        bf16x8 p;
#pragma unroll
        for (int j = 0; j < 8; ++j) {
            float v = (n < REL_) ? W2[(size_t)(k0 + j) * REL_ + n] : 0.f;
            p[j] = f2bf(v);
        }
        *(bf16x8*)(W2T + (size_t)n * HID_ + k0) = p;
    } else {
        int g   = (blk - 4704) * 192 + tid;
        int sel = g >= 7680;
        int gg  = sel ? g - 7680 : g;
        int i   = gg / HID_;
        int n   = gg - i * HID_;
        int rb  = sel ? 1556 : 768;
        float a = 0.f;
#pragma unroll
        for (int j = 0; j < DIS_; ++j)
            a += dis[i * DIS_ + j] * W1[(size_t)(rb + j) * HID_ + n];
        (sel ? disT : disH)[i * HID_ + n] = a;
    }
}

__global__ __launch_bounds__(192) void vertex_kernel(
    const ushort_t* __restrict__ span_emb, const int* __restrict__ vidx,
    const int* __restrict__ vmask, ushort_t* __restrict__ vembB)
{
    int bv = blockIdx.x;
    int b  = bv >> 7;
    const int* vi = vidx  + bv * C_;
    const int* vm = vmask + bv * C_;
    int   idxs[C_];
    float ms[C_];
    float cnt = 0.f;
#pragma unroll
    for (int c = 0; c < C_; ++c) {
        idxs[c] = vi[c];
        ms[c]   = (float)vm[c];
        cnt    += ms[c];
    }
    float inv = 1.f / fmaxf(cnt, 1.f);
    int col = threadIdx.x * 4;
    float s[4] = {0.f, 0.f, 0.f, 0.f};
#pragma unroll
    for (int c = 0; c < C_; ++c) {
        if (ms[c] != 0.f) {
            bf16x4 x = *(const bf16x4*)(span_emb +
                        ((size_t)(b * NS_ + idxs[c])) * D_ + col);
#pragma unroll
            for (int q = 0; q < 4; ++q) s[q] += bf2f(x[q]);
        }
    }
    bf16x4 o;
#pragma unroll
    for (int q = 0; q < 4; ++q) o[q] = f2bf(s[q] * inv);
    *(bf16x4*)(vembB + (size_t)bv * D_ + col) = o;
}

__global__ __launch_bounds__(256, 3) void gemmc_kernel(
    const ushort_t* __restrict__ vembB, const ushort_t* __restrict__ W1HT,
    float* __restrict__ vproj)
{
    __shared__ ushort_t Abuf[2][64][64];
    __shared__ ushort_t Bbuf[2][8][64][8];

    int tid  = threadIdx.x;
    int wv   = tid >> 6;
    int lane = tid & 63;
    int m0   = blockIdx.x * 64;
    int nt   = blockIdx.y;
    int n0   = nt * 64;

    int rr  = lane >> 3;
    int sl  = lane & 7;
    int gsw = (sl - rr) & 7;

    const ushort_t* asrc[2];
#pragma unroll
    for (int gi = 0; gi < 2; ++gi)
        asrc[gi] = vembB + (size_t)(m0 + wv * 16 + gi * 8 + rr) * KD_ + gsw * 8;

    auto stage = [&](int bf, int it) {
#pragma unroll
        for (int gi = 0; gi < 2; ++gi)
            dma16(asrc[gi] + it * 64, &Abuf[bf][wv * 16 + gi * 8][0]);
        const ushort_t* bbase = W1HT + ((size_t)it * 12 + nt) * 4096;
#pragma unroll
        for (int q = 0; q < 2; ++q) {
            int p = wv * 2 + q;
            dma16(bbase + (size_t)p * 512 + lane * 8, &Bbuf[bf][p][0][0]);
        }
    };

    int half = lane >> 5;
    int lrow = lane & 31;
    int wm   = (wv & 1) * 32;
    int wn   = (wv >> 1) * 32;

    f32x16 acc;
#pragma unroll
    for (int r = 0; r < 16; ++r) acc[r] = 0.f;

    stage(0, 0);
    for (int it = 0; it < 12; ++it) {
        int bf = it & 1;
        __syncthreads();
        if (it + 1 < 12) stage(bf ^ 1, it + 1);
#pragma unroll
        for (int s = 0; s < 4; ++s) {
            int kg   = s * 2 + half;
            int slot = ((kg + lrow) & 7) * 8;
            bf16x8 a = *(bf16x8*)&Abuf[bf][wm + lrow][slot];
            bf16x8 b = *(bf16x8*)&Bbuf[bf][kg][wn + lrow][0];
            acc = __builtin_amdgcn_mfma_f32_32x32x16_bf16(a, b, acc, 0, 0, 0);
        }
    }

    int col = n0 + wn + lrow;
#pragma unroll
    for (int r = 0; r < 16; ++r) {
        int row = m0 + wm + (r & 3) + 8 * (r >> 2) + 4 * half;
        vproj[(size_t)row * KD_ + col] = acc[r];
    }
}

__global__ __launch_bounds__(256, 3) void gemmd_kernel(
    const ushort_t* __restrict__ vembB, const int* __restrict__ ht,
    const int* __restrict__ dht, const int* __restrict__ dth,
    const ushort_t* __restrict__ W1P, const float* __restrict__ vproj,
    const float* __restrict__ disH, const float* __restrict__ disT,
    ushort_t* __restrict__ hidden)
{
    __shared__ ushort_t Abuf[2][64][64];
    __shared__ ushort_t Bbuf[2][8][64][8];
    __shared__ int hI[64], tI[64], dhI[64], dtI[64];

    int tid  = threadIdx.x;
    int wv   = tid >> 6;
    int lane = tid & 63;
    int m0   = blockIdx.x * 64;
    int nt   = blockIdx.y;
    int n0   = nt * 64;

    int rr  = lane >> 3;
    int sl  = lane & 7;
    int gsw = (sl - rr) & 7;

    if (tid < 64) {
        int g = m0 + tid;
        int b = g >> 9;
        hI[tid]  = b * V_ + ht[2 * g];
        tI[tid]  = b * V_ + ht[2 * g + 1];
        dhI[tid] = dht[g];
        dtI[tid] = dth[g];
    }

    int hoff[2], toff[2];
#pragma unroll
    for (int gi = 0; gi < 2; ++gi) {
        int g = m0 + wv * 16 + gi * 8 + rr;
        int b = g >> 9;
        hoff[gi] = (b * V_ + ht[2 * g])     * KD_;
        toff[gi] = (b * V_ + ht[2 * g + 1]) * KD_;
    }

    auto stage = [&](int bf, int it) {
        int kk = it * 64 + gsw * 8;
#pragma unroll
        for (int gi = 0; gi < 2; ++gi) {
            bf16x8 h = *(const bf16x8*)(vembB + hoff[gi] + kk);
            bf16x8 t = *(const bf16x8*)(vembB + toff[gi] + kk);
            bf16x8 p;
#pragma unroll
            for (int j = 0; j < 8; ++j) p[j] = f2bf(bf2f(h[j]) * bf2f(t[j]));
            *(bf16x8*)&Abuf[bf][wv * 16 + gi * 8 + rr][sl * 8] = p;
        }
        const ushort_t* bbase = W1P + ((size_t)it * 6 + nt) * 4096;
#pragma unroll
        for (int q = 0; q < 2; ++q) {
            int p = wv * 2 + q;
            dma16(bbase + (size_t)p * 512 + lane * 8, &Bbuf[bf][p][0][0]);
        }
    };

    int half = lane >> 5;
    int lrow = lane & 31;
    int wm   = (wv & 1) * 32;
    int wn   = (wv >> 1) * 32;

    f32x16 acc;
#pragma unroll
    for (int r = 0; r < 16; ++r) acc[r] = 0.f;

    stage(0, 0);
    for (int it = 0; it < 12; ++it) {
        int bf = it & 1;
        __syncthreads();
        if (it + 1 < 12) stage(bf ^ 1, it + 1);
#pragma unroll
        for (int s = 0; s < 4; ++s) {
            int kg   = s * 2 + half;
            int slot = ((kg + lrow) & 7) * 8;
            bf16x8 a = *(bf16x8*)&Abuf[bf][wm + lrow][slot];
            bf16x8 b = *(bf16x8*)&Bbuf[bf][kg][wn + lrow][0];
            acc = __builtin_amdgcn_mfma_f32_32x32x16_bf16(a, b, acc, 0, 0, 0);
        }
    }

    int col = n0 + wn + lrow;
#pragma unroll
    for (int r = 0; r < 16; ++r) {
        int rl = wm + (r & 3) + 8 * (r >> 2) + 4 * half;
        float v = acc[r]
                + vproj[(size_t)hI[rl] * KD_ + col]
                + vproj[(size_t)tI[rl] * KD_ + HID_ + col]
                + disH[dhI[rl] * HID_ + col]
                + disT[dtI[rl] * HID_ + col];
        hidden[(size_t)(m0 + rl) * HID_ + col] = (ushort_t)f2bf(fmaxf(v, 0.f));
    }
}

__global__ __launch_bounds__(256) void gemm2_kernel(
    const ushort_t* __restrict__ hidden, const ushort_t* __restrict__ W2T,
    const float* __restrict__ b2, float* __restrict__ out)
{
    __shared__ ushort_t As[32][72];
    __shared__ ushort_t Bs[128][72];

    int m0  = blockIdx.x * 32;
    int tid = threadIdx.x;

    int arow = tid >> 3;
    int akk  = (tid & 7) * 8;

    bf16x8 pA; bf16x8 pB[4];
    auto loadAB = [&](int k0) {
        pA = *(const bf16x8*)(hidden + (size_t)(m0 + arow) * HID_ + k0 + akk);
#pragma unroll
        for (int e = 0; e < 4; ++e)
            pB[e] = *(const bf16x8*)(W2T + (size_t)(arow + e * 32) * HID_ + k0 + akk);
    };

    int w    = tid >> 6;
    int lane = tid & 63;
    int wm = (w & 1) * 16;
    int wn = (w >> 1) * 64;
    int lr = lane & 15, lq = lane >> 4;

    f32x4 acc[4];
#pragma unroll
    for (int e = 0; e < 4; ++e) acc[e] = (f32x4){0.f, 0.f, 0.f, 0.f};

    loadAB(0);
    for (int k0 = 0; k0 < HID_; k0 += 64) {
        __syncthreads();
        *(bf16x8*)&As[arow][akk] = pA;
#pragma unroll
        for (int e = 0; e < 4; ++e)
            *(bf16x8*)&Bs[arow + e * 32][akk] = pB[e];
        __syncthreads();
        if (k0 + 64 < HID_) loadAB(k0 + 64);
#pragma unroll
        for (int ks = 0; ks < 2; ++ks) {
            int kb = ks * 32 + lq * 8;
            bf16x8 a = *(bf16x8*)&As[wm + lr][kb];
#pragma unroll
            for (int nf = 0; nf < 4; ++nf) {
                bf16x8 bb = *(bf16x8*)&Bs[wn + nf * 16 + lr][kb];
                acc[nf] = __builtin_amdgcn_mfma_f32_16x16x32_bf16(a, bb, acc[nf], 0, 0, 0);
            }
        }
    }

    int grow = m0 + wm + lq * 4;
#pragma unroll
    for (int nf = 0; nf < 4; ++nf) {
        int col = wn + nf * 16 + lr;
        if (col < REL_) {
            float bias = b2[col];
#pragma unroll
            for (int r = 0; r < 4; ++r)
                out[(size_t)(grow + r) * REL_ + col] = acc[nf][r] + bias;
        }
    }
}

// ---------------------------------------------------------------------------
extern "C" void kernel_launch(void* const* d_in, const int* in_sizes, int n_in,
                              void* d_out, int out_size, void* d_ws, size_t ws_size,
                              hipStream_t stream)
{
    const float* sr    = (const float*)d_in[0];
    const int*   spans = (const int*)  d_in[1];
    const int*   vidx  = (const int*)  d_in[3];
    const int*   vmask = (const int*)  d_in[4];
    const int*   ht    = (const int*)  d_in[5];
    const int*   dht   = (const int*)  d_in[7];
    const int*   dth   = (const int*)  d_in[8];
    const float* dis   = (const float*)d_in[9];
    const float* W1    = (const float*)d_in[10];
    const float* W2    = (const float*)d_in[11];
    const float* b2    = (const float*)d_in[12];
    float* out = (float*)d_out;

    ushort_t* span_emb = (ushort_t*)d_ws;                     // 4096*768
    ushort_t* vembB    = span_emb + (size_t)B_ * NS_ * D_;    // 2048*768
    ushort_t* W1HT     = vembB + (size_t)B_ * V_ * D_;        // 144*4096
    ushort_t* W1P      = W1HT + (size_t)144 * 4096;           // 72*4096
    ushort_t* W2T      = W1P + (size_t)72 * 4096;             // 128*384
    ushort_t* hidden   = W2T + (size_t)N2P_ * HID_;           // 8192*384
    float* vproj = (float*)(hidden + (size_t)B_ * R_ * HID_); // 2048*768 f32
    float* disH  = vproj + (size_t)B_ * V_ * KD_;             // 20*384 f32
    float* disT  = disH + (size_t)DIS_ * HID_;                // 20*384 f32

    // --- try cooperative mega-kernel (only outside graph capture) ---
    bool done = false;
    hipStreamCaptureStatus cs = hipStreamCaptureStatusNone;
    if (hipStreamIsCapturing(stream, &cs) != hipSuccess)
        cs = hipStreamCaptureStatusActive;     // unknown -> be conservative
    if (cs == hipStreamCaptureStatusNone) {
        int maxB = 0;
        if (hipOccupancyMaxActiveBlocksPerMultiprocessor(&maxB, mega_kernel,
                                                         NTHR, 0) == hipSuccess
            && maxB >= 1) {
            int nblk = 256 * maxB;
            if (nblk > NBLK) nblk = NBLK;
            void* args[] = {
                (void*)&sr, (void*)&spans, (void*)&vidx, (void*)&vmask,
                (void*)&ht, (void*)&dht, (void*)&dth, (void*)&dis,
                (void*)&W1, (void*)&W2, (void*)&b2,
                (void*)&span_emb, (void*)&vembB, (void*)&W1HT, (void*)&W1P,
                (void*)&W2T, (void*)&disH, (void*)&disT, (void*)&hidden,
                (void*)&vproj, (void*)&out
            };
            if (hipLaunchCooperativeKernel((void*)mega_kernel, dim3(nblk),
                                           dim3(NTHR), args, 0, stream)
                == hipSuccess)
                done = true;
            else
                (void)hipGetLastError();       // clear sticky error
        }
    }

    if (!done) {
        // --- verified five-kernel fallback ---
        prep_kernel<<<4784, 192, 0, stream>>>(
            sr, spans, W1, W2, dis, span_emb, W1HT, W1P, W2T, disH, disT);
        vertex_kernel<<<B_ * V_, 192, 0, stream>>>(span_emb, vidx, vmask, vembB);
        gemmc_kernel<<<dim3(32, 12), 256, 0, stream>>>(vembB, W1HT, vproj);
        gemmd_kernel<<<dim3(128, 6), 256, 0, stream>>>(
            vembB, ht, dht, dth, W1P, vproj, disH, disT, hidden);
        gemm2_kernel<<<(B_ * R_) / 32, 256, 0, stream>>>(hidden, W2T, b2, out);
    }
}